// Round 7
// baseline (460.435 us; speedup 1.0000x reference)
//
#include <hip/hip_runtime.h>
#include <math.h>

#define ALPHA 0.2f
#define NEGV  -9e15f
#define EPSV  1e-5f

constexpr int B_ = 2, N_ = 4096, F_ = 256, H_ = 1024;
constexpr int SPLIT_ = 16;   // colstats i-split
constexpr int SPLITJ_ = 4;   // attention j-split

typedef __attribute__((ext_vector_type(4))) float f32x4;
typedef __attribute__((ext_vector_type(8))) short s16x8;

__device__ __forceinline__ unsigned short f2bf(float f) {
    unsigned u = __builtin_bit_cast(unsigned, f);
    u += 0x7fffu + ((u >> 16) & 1u);
    return (unsigned short)(u >> 16);
}
__device__ __forceinline__ float bf2f(unsigned short h) {
    unsigned u = ((unsigned)h) << 16;
    return __builtin_bit_cast(float, u);
}

// ---------------- batched weight transpose + bf16 (+ zero of Wh scratch) -------
__global__ __launch_bounds__(256) void transp_all_kernel(
    const float* __restrict__ W1, const float* __restrict__ W2,
    const float* __restrict__ F1s, const float* __restrict__ F2s,
    unsigned short* __restrict__ D1, unsigned short* __restrict__ D2,
    unsigned short* __restrict__ D3, unsigned short* __restrict__ D4,
    float* __restrict__ zeroDst)
{
    const int mi = blockIdx.z;
    const int t = threadIdx.x;
    if (mi == 4) {
        const int bid = blockIdx.y * 16 + blockIdx.x;
        if (bid < 32) {
            const int i = (bid * 256 + t) * 4;
            *(float4*)&zeroDst[i] = make_float4(0.f, 0.f, 0.f, 0.f);
        }
        return;
    }
    const float* src; unsigned short* dst; int R, Cc;
    if (mi == 0)      { src = W1;  dst = D1; R = 256;  Cc = 256; }
    else if (mi == 1) { src = W2;  dst = D2; R = 256;  Cc = 256; }
    else if (mi == 2) { src = F1s; dst = D3; R = 256;  Cc = 1024; }
    else              { src = F2s; dst = D4; R = 1024; Cc = 256; }
    const int r0 = blockIdx.x * 64, c0 = blockIdx.y * 64;
    if (r0 >= R || c0 >= Cc) return;

    __shared__ float T[64][65];
    #pragma unroll
    for (int s = 0; s < 4; ++s) {
        const int rr = s * 16 + (t >> 4);
        const int cq = t & 15;
        const float4 v = *(const float4*)&src[(size_t)(r0 + rr) * Cc + c0 + cq * 4];
        T[rr][cq * 4 + 0] = v.x; T[rr][cq * 4 + 1] = v.y;
        T[rr][cq * 4 + 2] = v.z; T[rr][cq * 4 + 3] = v.w;
    }
    __syncthreads();
    #pragma unroll
    for (int s = 0; s < 4; ++s) {
        const int cr = s * 16 + (t >> 4);
        const int rq = t & 15;
        ushort4 o;
        o.x = f2bf(T[rq * 4 + 0][cr]);
        o.y = f2bf(T[rq * 4 + 1][cr]);
        o.z = f2bf(T[rq * 4 + 2][cr]);
        o.w = f2bf(T[rq * 4 + 3][cr]);
        *(ushort4*)&dst[(size_t)(c0 + cr) * R + r0 + rq * 4] = o;
    }
}

// ---------------- 128x128 bf16 MFMA GEMM (M fixed 8192) ------------------------
__global__ __launch_bounds__(256) void gemm128_kernel(
    const void* __restrict__ Ap, const unsigned short* __restrict__ Wt,
    const float* __restrict__ bias, void* __restrict__ Cp,
    unsigned short* __restrict__ Tout, const float* __restrict__ wha,
    float* __restrict__ Wh1, float* __restrict__ Wh2,
    int Nc, int K, int relu, int a_bf16, int c_mode)
{
    __shared__ unsigned short As[128 * 72];
    __shared__ unsigned short Bs[128 * 72];
    const int t = threadIdx.x;
    const int w = t >> 6, l = t & 63;
    const int quad = l >> 4, l15 = l & 15;
    const int wr = w & 1, wc = w >> 1;
    const int row0 = blockIdx.y * 128, col0 = blockIdx.x * 128;
    const int sr = t >> 1;
    const int sk = (t & 1) * 32;

    f32x4 acc[4][4];
    #pragma unroll
    for (int it = 0; it < 4; ++it)
        #pragma unroll
        for (int ft = 0; ft < 4; ++ft) acc[it][ft] = (f32x4)(0.f);

    for (int k0 = 0; k0 < K; k0 += 64) {
        if (a_bf16) {
            const unsigned short* ap =
                (const unsigned short*)Ap + (size_t)(row0 + sr) * K + k0 + sk;
            #pragma unroll
            for (int u = 0; u < 4; ++u)
                *(s16x8*)&As[sr * 72 + sk + u * 8] = *(const s16x8*)(ap + u * 8);
        } else {
            const float* ap = (const float*)Ap + (size_t)(row0 + sr) * K + k0 + sk;
            #pragma unroll
            for (int u = 0; u < 8; ++u) {
                const float4 v = *(const float4*)(ap + u * 4);
                ushort4 o;
                o.x = f2bf(v.x); o.y = f2bf(v.y); o.z = f2bf(v.z); o.w = f2bf(v.w);
                *(ushort4*)&As[sr * 72 + sk + u * 4] = o;
            }
        }
        {
            const unsigned short* bp = Wt + (size_t)(col0 + sr) * K + k0 + sk;
            #pragma unroll
            for (int u = 0; u < 4; ++u)
                *(s16x8*)&Bs[sr * 72 + sk + u * 8] = *(const s16x8*)(bp + u * 8);
        }
        __syncthreads();
        #pragma unroll
        for (int ks = 0; ks < 64; ks += 32) {
            s16x8 af[4], bf[4];
            #pragma unroll
            for (int it = 0; it < 4; ++it)
                af[it] = *(const s16x8*)&As[(wr * 64 + it * 16 + l15) * 72 + ks + quad * 8];
            #pragma unroll
            for (int ft = 0; ft < 4; ++ft)
                bf[ft] = *(const s16x8*)&Bs[(wc * 64 + ft * 16 + l15) * 72 + ks + quad * 8];
            #pragma unroll
            for (int ft = 0; ft < 4; ++ft)
                #pragma unroll
                for (int it = 0; it < 4; ++it)
                    acc[it][ft] = __builtin_amdgcn_mfma_f32_16x16x32_bf16(
                        af[it], bf[ft], acc[it][ft], 0, 0, 0);
        }
        __syncthreads();
    }

    if (c_mode) {
        #pragma unroll
        for (int ft = 0; ft < 4; ++ft) {
            const int col = col0 + wc * 64 + ft * 16 + l15;
            const float bv = bias ? bias[col] : 0.f;
            #pragma unroll
            for (int it = 0; it < 4; ++it) {
                const int rbase = row0 + wr * 64 + it * 16 + quad * 4;
                #pragma unroll
                for (int rr = 0; rr < 4; ++rr) {
                    float v = acc[it][ft][rr] + bv;
                    if (relu) v = fmaxf(v, 0.f);
                    if (c_mode == 2)
                        ((unsigned short*)Cp)[(size_t)(rbase + rr) * Nc + col] = f2bf(v);
                    else
                        ((float*)Cp)[(size_t)(rbase + rr) * Nc + col] = v;
                }
            }
        }
    }

    if (Tout) {
        const int bb = row0 >> 12;
        #pragma unroll
        for (int ft = 0; ft < 4; ++ft) {
            const int col = col0 + wc * 64 + ft * 16 + l15;
            #pragma unroll
            for (int it = 0; it < 4; ++it) {
                const int ibase = (row0 & (N_ - 1)) + wr * 64 + it * 16 + quad * 4;
                ushort4 o;
                o.x = f2bf(acc[it][ft][0]); o.y = f2bf(acc[it][ft][1]);
                o.z = f2bf(acc[it][ft][2]); o.w = f2bf(acc[it][ft][3]);
                *(ushort4*)&Tout[((size_t)bb * F_ + col) * N_ + ibase] = o;
            }
        }
    }

    if (wha) {
        float a1v[4], a2v[4];
        #pragma unroll
        for (int ft = 0; ft < 4; ++ft) {
            const int col = col0 + wc * 64 + ft * 16 + l15;
            a1v[ft] = wha[col];
            a2v[ft] = wha[F_ + col];
        }
        #pragma unroll
        for (int it = 0; it < 4; ++it)
            #pragma unroll
            for (int rr = 0; rr < 4; ++rr) {
                float s1 = 0.f, s2 = 0.f;
                #pragma unroll
                for (int ft = 0; ft < 4; ++ft) {
                    s1 += acc[it][ft][rr] * a1v[ft];
                    s2 += acc[it][ft][rr] * a2v[ft];
                }
                #pragma unroll
                for (int mkk = 1; mkk < 16; mkk <<= 1) {
                    s1 += __shfl_xor(s1, mkk);
                    s2 += __shfl_xor(s2, mkk);
                }
                if (l15 == 0) {
                    const int row = row0 + wr * 64 + it * 16 + quad * 4 + rr;
                    atomicAdd(&Wh1[row], s1);
                    atomicAdd(&Wh2[row], s2);
                }
            }
    }
}

// ---------------- layer-1: adj -> stats + bitmask (fused, 8-wide ILP) ----------
__global__ __launch_bounds__(256) void colstats_adj_kernel(
    const int* __restrict__ adj, unsigned long long* __restrict__ maskOut,
    const float* __restrict__ Wh1, const float* __restrict__ Wh2,
    float* __restrict__ pM, float* __restrict__ pS)
{
    const int t = threadIdx.x;
    const int j = blockIdx.x * 256 + t;
    const int sp = blockIdx.y;
    const int b = blockIdx.z;
    const int i0 = sp * (N_ / SPLIT_);
    const int w = t >> 6, l = t & 63;
    const float w2 = Wh2[b * N_ + j];
    const float* __restrict__ w1p = Wh1 + b * N_ + i0;
    const int* __restrict__ ap = adj + ((size_t)b * N_ + i0) * N_ + j;

    float m = -3.4e38f, s = 0.f;
    for (int c = 0; c < N_ / SPLIT_; c += 8) {
        int v[8];
        #pragma unroll
        for (int u = 0; u < 8; ++u) v[u] = ap[(size_t)(c + u) * N_];
        float x[8];
        #pragma unroll
        for (int u = 0; u < 8; ++u) {
            const bool act = v[u] > 0;
            const unsigned long long bm = __ballot(act);
            if (l == 0)
                maskOut[((size_t)b * N_ + i0 + c + u) * (N_ / 64) + blockIdx.x * 4 + w] = bm;
            const float e0 = w1p[c + u] + w2;
            const float e = fmaxf(e0, ALPHA * e0);
            x[u] = act ? e : NEGV;
        }
        const float cm = fmaxf(fmaxf(fmaxf(x[0], x[1]), fmaxf(x[2], x[3])),
                               fmaxf(fmaxf(x[4], x[5]), fmaxf(x[6], x[7])));
        const float nm = fmaxf(m, cm);
        float cs = 0.f;
        #pragma unroll
        for (int u = 0; u < 8; ++u) cs += __expf(x[u] - nm);
        s = s * __expf(m - nm) + cs;
        m = nm;
    }
    pM[((size_t)b * SPLIT_ + sp) * N_ + j] = m;
    pS[((size_t)b * SPLIT_ + sp) * N_ + j] = s;
}

// ---------------- layer-2: stats from bitmask ----------------------------------
__global__ __launch_bounds__(256) void colstats3_kernel(
    const unsigned long long* __restrict__ mask,
    const float* __restrict__ Wh1, const float* __restrict__ Wh2,
    float* __restrict__ pM, float* __restrict__ pS)
{
    const int t = threadIdx.x;
    const int j = blockIdx.x * 256 + t;
    const int sp = blockIdx.y;
    const int b = blockIdx.z;
    const int i0 = sp * (N_ / SPLIT_);
    const int w = t >> 6;
    const int jbit = t & 63;
    const float w2 = Wh2[b * N_ + j];
    const unsigned long long* __restrict__ mbase =
        mask + ((size_t)b * N_ + i0) * (N_ / 64) + blockIdx.x * 4 + w;
    const float* __restrict__ w1p = Wh1 + b * N_ + i0;

    float m = -3.4e38f, s = 0.f;
    for (int c = 0; c < N_ / SPLIT_; c += 8) {
        float x[8];
        #pragma unroll
        for (int u = 0; u < 8; ++u) {
            const unsigned long long mw = mbase[(size_t)(c + u) * (N_ / 64)];
            const float e0 = w1p[c + u] + w2;
            const float e = fmaxf(e0, ALPHA * e0);
            x[u] = ((mw >> jbit) & 1ull) ? e : NEGV;
        }
        const float cm = fmaxf(fmaxf(fmaxf(x[0], x[1]), fmaxf(x[2], x[3])),
                               fmaxf(fmaxf(x[4], x[5]), fmaxf(x[6], x[7])));
        const float nm = fmaxf(m, cm);
        float cs = 0.f;
        #pragma unroll
        for (int u = 0; u < 8; ++u) cs += __expf(x[u] - nm);
        s = s * __expf(m - nm) + cs;
        m = nm;
    }
    pM[((size_t)b * SPLIT_ + sp) * N_ + j] = m;
    pS[((size_t)b * SPLIT_ + sp) * N_ + j] = s;
}

// ---------------- attention matmul: LDS-free B, fused colfin, bf16 partials ----
// grid (N/64, SPLITJ, B), block 256 (4 waves), 4 blocks/CU target.
__global__ __launch_bounds__(256, 4) void att_dir_kernel(
    const unsigned short* __restrict__ mask16, const unsigned short* __restrict__ Wht,
    const float* __restrict__ Wh1, const float* __restrict__ Wh2,
    const float* __restrict__ pM, const float* __restrict__ pS,
    unsigned short* __restrict__ partb)
{
    __shared__ unsigned short Ps[64 * 72];
    __shared__ float w2s[1024];
    __shared__ float mos[1024];

    const int t = threadIdx.x;
    const int w = t >> 6, l = t & 63;
    const int quad = l >> 4, l15 = l & 15;
    const int b = blockIdx.z;
    const int i0 = blockIdx.x * 64;
    const int sp = blockIdx.y;
    const int jbase = sp * (N_ / SPLITJ_);

    const int pi = t >> 2;
    const int pj4 = t & 3;
    const float w1i = Wh1[b * N_ + i0 + pi];
    const unsigned short* __restrict__ mrow =
        mask16 + ((size_t)b * N_ + i0 + pi) * (N_ / 16);
    const unsigned short* __restrict__ WhtB = Wht + (size_t)b * F_ * N_;

    // ---- fused colfin: mo = m + ln(sum) for this block's 1024-j range ----
    {
        const int jg = jbase + t * 4;
        float4 m4 = make_float4(-3.4e38f, -3.4e38f, -3.4e38f, -3.4e38f);
        #pragma unroll
        for (int s = 0; s < SPLIT_; ++s) {
            const float4 v = *(const float4*)&pM[((size_t)b * SPLIT_ + s) * N_ + jg];
            m4.x = fmaxf(m4.x, v.x); m4.y = fmaxf(m4.y, v.y);
            m4.z = fmaxf(m4.z, v.z); m4.w = fmaxf(m4.w, v.w);
        }
        float4 s4 = make_float4(0.f, 0.f, 0.f, 0.f);
        #pragma unroll
        for (int s = 0; s < SPLIT_; ++s) {
            const float4 vm = *(const float4*)&pM[((size_t)b * SPLIT_ + s) * N_ + jg];
            const float4 vs = *(const float4*)&pS[((size_t)b * SPLIT_ + s) * N_ + jg];
            s4.x += vs.x * __expf(vm.x - m4.x);
            s4.y += vs.y * __expf(vm.y - m4.y);
            s4.z += vs.z * __expf(vm.z - m4.z);
            s4.w += vs.w * __expf(vm.w - m4.w);
        }
        float4 mo4;
        mo4.x = m4.x + __logf(s4.x);
        mo4.y = m4.y + __logf(s4.y);
        mo4.z = m4.z + __logf(s4.z);
        mo4.w = m4.w + __logf(s4.w);
        *(float4*)&mos[t * 4] = mo4;
        *(float4*)&w2s[t * 4] = *(const float4*)&Wh2[b * N_ + jg];
    }

    f32x4 acc[4][4];
    #pragma unroll
    for (int it = 0; it < 4; ++it)
        #pragma unroll
        for (int ft = 0; ft < 4; ++ft) acc[it][ft] = (f32x4)(0.f);

    unsigned short mb_cur = mrow[jbase / 16 + pj4];
    unsigned short mb_next = 0;
    __syncthreads();   // stats LDS ready

    constexpr int NITER = (N_ / SPLITJ_) / 64;
    for (int itr = 0; itr < NITER; ++itr) {
        const int jb = jbase + itr * 64;
        // ---- P gen (stats from LDS) ----
        {
            const unsigned mb = mb_cur;
            const int jl = itr * 64 + pj4 * 16;
            #pragma unroll
            for (int u4 = 0; u4 < 4; ++u4) {
                const float4 w2v = *(const float4*)&w2s[jl + u4 * 4];
                const float4 mov = *(const float4*)&mos[jl + u4 * 4];
                ushort4 o;
                unsigned short* op = &o.x;
                #pragma unroll
                for (int u = 0; u < 4; ++u) {
                    const float xw = w1i + (&w2v.x)[u];
                    const float e = fmaxf(xw, ALPHA * xw);
                    const float x2 = ((mb >> (u4 * 4 + u)) & 1u) ? e : NEGV;
                    op[u] = f2bf(__expf(x2 - (&mov.x)[u]));
                }
                *(ushort4*)&Ps[pi * 72 + pj4 * 16 + u4 * 4] = o;
            }
        }
        __syncthreads();
        if (itr + 1 < NITER) mb_next = mrow[(jb + 64) / 16 + pj4];
        // ---- MFMA: B fragments direct from global (L2-resident Wht) ----
        #pragma unroll
        for (int ks = 0; ks < 64; ks += 32) {
            s16x8 bf[4];
            #pragma unroll
            for (int ft = 0; ft < 4; ++ft)
                bf[ft] = *(const s16x8*)&WhtB[(size_t)(w * 64 + ft * 16 + l15) * N_
                                              + jb + ks + quad * 8];
            s16x8 af[4];
            #pragma unroll
            for (int it = 0; it < 4; ++it)
                af[it] = *(const s16x8*)&Ps[(it * 16 + l15) * 72 + ks + quad * 8];
            #pragma unroll
            for (int ft = 0; ft < 4; ++ft)
                #pragma unroll
                for (int it = 0; it < 4; ++it)
                    acc[it][ft] = __builtin_amdgcn_mfma_f32_16x16x32_bf16(
                        af[it], bf[ft], acc[it][ft], 0, 0, 0);
        }
        __syncthreads();
        mb_cur = mb_next;
    }

    // ---- epilogue: bf16 partials [sp][b][i][f] ----
    unsigned short* __restrict__ pout = partb + ((size_t)sp * B_ + b) * N_ * F_;
    #pragma unroll
    for (int it = 0; it < 4; ++it)
        #pragma unroll
        for (int ft = 0; ft < 4; ++ft) {
            const int col = w * 64 + ft * 16 + l15;
            #pragma unroll
            for (int rr = 0; rr < 4; ++rr) {
                const int row = i0 + it * 16 + quad * 4 + rr;
                pout[(size_t)row * F_ + col] = f2bf(acc[it][ft][rr]);
            }
        }
}

// ---------------- bf16 partial reduction (4 splits) -> bf16 --------------------
__global__ __launch_bounds__(256) void reduceb_kernel(
    const unsigned short* __restrict__ p, unsigned short* __restrict__ outb)
{
    const size_t i = ((size_t)blockIdx.x * 256 + threadIdx.x) * 8;
    const size_t S = (size_t)B_ * N_ * F_;
    float acc[8] = {};
    #pragma unroll
    for (int u = 0; u < 4; ++u) {
        const ushort4 a = *(const ushort4*)&p[i + u * S];
        const ushort4 c = *(const ushort4*)&p[i + u * S + 4];
        acc[0] += bf2f(a.x); acc[1] += bf2f(a.y);
        acc[2] += bf2f(a.z); acc[3] += bf2f(a.w);
        acc[4] += bf2f(c.x); acc[5] += bf2f(c.y);
        acc[6] += bf2f(c.z); acc[7] += bf2f(c.w);
    }
    ushort4 o0, o1;
    o0.x = f2bf(acc[0]); o0.y = f2bf(acc[1]); o0.z = f2bf(acc[2]); o0.w = f2bf(acc[3]);
    o1.x = f2bf(acc[4]); o1.y = f2bf(acc[5]); o1.z = f2bf(acc[6]); o1.w = f2bf(acc[7]);
    *(ushort4*)&outb[i] = o0;
    *(ushort4*)&outb[i + 4] = o1;
}

// ---------------- x + 4-way bf16 partial sum + LayerNorm -> fp32 + bf16 --------
__global__ __launch_bounds__(256) void addln4_kernel(
    const float* __restrict__ X, const unsigned short* __restrict__ pb,
    const float* __restrict__ g, const float* __restrict__ bta,
    float* __restrict__ outf, unsigned short* __restrict__ outb)
{
    const int row = blockIdx.x;
    const int t = threadIdx.x;
    const size_t idx = (size_t)row * F_ + t;
    const size_t S = (size_t)B_ * N_ * F_;
    const float v = X[idx] + bf2f(pb[idx]) + bf2f(pb[idx + S])
                  + bf2f(pb[idx + 2 * S]) + bf2f(pb[idx + 3 * S]);
    float s1 = v, s2 = v * v;
    #pragma unroll
    for (int off = 32; off > 0; off >>= 1) {
        s1 += __shfl_down(s1, off);
        s2 += __shfl_down(s2, off);
    }
    __shared__ float r1[4], r2[4];
    __shared__ float mu_s, rs_s;
    const int wid = t >> 6, lane = t & 63;
    if (lane == 0) { r1[wid] = s1; r2[wid] = s2; }
    __syncthreads();
    if (t == 0) {
        const float a = r1[0] + r1[1] + r1[2] + r1[3];
        const float q = r2[0] + r2[1] + r2[2] + r2[3];
        const float mu = a * (1.f / F_);
        const float var = q * (1.f / F_) - mu * mu;
        mu_s = mu;
        rs_s = rsqrtf(var + EPSV);
    }
    __syncthreads();
    const float r = (v - mu_s) * rs_s * g[t] + bta[t];
    outf[idx] = r;
    outb[idx] = f2bf(r);
}

// ---------------- residual add + LayerNorm (final) -----------------------------
__global__ __launch_bounds__(256) void addln_kernel(
    const float* __restrict__ X, const float* __restrict__ Y,
    const float* __restrict__ g, const float* __restrict__ bta,
    float* __restrict__ out)
{
    const int row = blockIdx.x;
    const int t = threadIdx.x;
    const size_t idx = (size_t)row * F_ + t;
    const float v = X[idx] + Y[idx];
    float s1 = v, s2 = v * v;
    #pragma unroll
    for (int off = 32; off > 0; off >>= 1) {
        s1 += __shfl_down(s1, off);
        s2 += __shfl_down(s2, off);
    }
    __shared__ float r1[4], r2[4];
    __shared__ float mu_s, rs_s;
    const int wid = t >> 6, lane = t & 63;
    if (lane == 0) { r1[wid] = s1; r2[wid] = s2; }
    __syncthreads();
    if (t == 0) {
        const float a = r1[0] + r1[1] + r1[2] + r1[3];
        const float q = r2[0] + r2[1] + r2[2] + r2[3];
        const float mu = a * (1.f / F_);
        const float var = q * (1.f / F_) - mu * mu;
        mu_s = mu;
        rs_s = rsqrtf(var + EPSV);
    }
    __syncthreads();
    out[idx] = (v - mu_s) * rs_s * g[t] + bta[t];
}

// -------------------------------------------------------------------------------
extern "C" void kernel_launch(void* const* d_in, const int* in_sizes, int n_in,
                              void* d_out, int out_size, void* d_ws, size_t ws_size,
                              hipStream_t stream)
{
    const float* x     = (const float*)d_in[0];
    const int*   adj   = (const int*)d_in[1];
    const float* W1    = (const float*)d_in[2];
    const float* a1    = (const float*)d_in[3];
    const float* W2    = (const float*)d_in[4];
    const float* a2    = (const float*)d_in[5];
    const float* w_ff1 = (const float*)d_in[6];
    const float* b_ff1 = (const float*)d_in[7];
    const float* w_ff2 = (const float*)d_in[8];
    const float* b_ff2 = (const float*)d_in[9];
    const float* g_ln1 = (const float*)d_in[10];
    const float* b_ln1 = (const float*)d_in[11];
    const float* g_ln2 = (const float*)d_in[12];
    const float* b_ln2 = (const float*)d_in[13];
    float* out = (float*)d_out;

    const int Rtot = B_ * N_;             // 8192
    char* wsb = (char*)d_ws;
    unsigned short* partb = (unsigned short*)wsb;                // 16 MB
    float* ln1   = (float*)(wsb + 16777216);                     // 8 MB
    float* ffout = (float*)(wsb + 25165824);                     // 8 MB
    unsigned short* mid  = (unsigned short*)(wsb + 33554432);    // 16 MB
    unsigned short* ln1b = (unsigned short*)(wsb + 50331648);    // 4 MB
    unsigned short* g1b  = (unsigned short*)(wsb + 54525952);    // 4 MB
    unsigned short* Wht  = (unsigned short*)(wsb + 58720256);    // 4 MB
    unsigned long long* mask = (unsigned long long*)(wsb + 62914560); // 4 MB
    unsigned short* mask16 = (unsigned short*)mask;
    unsigned short* Wt1  = (unsigned short*)(wsb + 67108864);    // 128 KB
    unsigned short* Wt2  = Wt1 + 65536;                          // 128 KB
    unsigned short* Wtf1 = Wt2 + 65536;                          // 512 KB
    unsigned short* Wtf2 = Wtf1 + 262144;                        // 512 KB
    float* WhA1 = (float*)(wsb + 69206016);                      // 32 KB zeroed
    float* WhA2 = WhA1 + 8192;
    float* WhB1 = WhA2 + 8192;
    float* WhB2 = WhB1 + 8192;
    float* pM   = (float*)(wsb + 69337088);                      // 512 KB
    float* pS   = (float*)(wsb + 69861376);                      // 512 KB

    const dim3 statsG(N_ / 256, SPLIT_, B_);
    const dim3 attG(N_ / 64, SPLITJ_, B_);

    // ===== prologue: weight transposes + zero atomic targets (one kernel) =====
    transp_all_kernel<<<dim3(16, 16, 5), 256, 0, stream>>>(
        W1, W2, w_ff1, w_ff2, Wt1, Wt2, Wtf1, Wtf2, WhA1);

    // ===== GAT layer 1 =====
    gemm128_kernel<<<dim3(2, 64), 256, 0, stream>>>(
        x, Wt1, nullptr, nullptr, Wht, a1, WhA1, WhA2, F_, F_, 0, 0, 0);
    colstats_adj_kernel<<<statsG, 256, 0, stream>>>(adj, mask, WhA1, WhA2, pM, pS);
    att_dir_kernel<<<attG, 256, 0, stream>>>(mask16, Wht, WhA1, WhA2, pM, pS, partb);
    reduceb_kernel<<<1024, 256, 0, stream>>>(partb, g1b);

    // ===== GAT layer 2 (mask reused) =====
    gemm128_kernel<<<dim3(2, 64), 256, 0, stream>>>(
        g1b, Wt2, nullptr, nullptr, Wht, a2, WhB1, WhB2, F_, F_, 0, 1, 0);
    colstats3_kernel<<<statsG, 256, 0, stream>>>(mask, WhB1, WhB2, pM, pS);
    att_dir_kernel<<<attG, 256, 0, stream>>>(mask16, Wht, WhB1, WhB2, pM, pS, partb);

    // ===== LN1(x + sum of 4 bf16 partials) -> ln1 fp32 + ln1b bf16 =====
    addln4_kernel<<<Rtot, 256, 0, stream>>>(x, partb, g_ln1, b_ln1, ln1, ln1b);

    // ===== FFN =====
    gemm128_kernel<<<dim3(8, 64), 256, 0, stream>>>(
        ln1b, Wtf1, b_ff1, mid, nullptr, nullptr, nullptr, nullptr, H_, F_, 1, 1, 2);
    gemm128_kernel<<<dim3(2, 64), 256, 0, stream>>>(
        mid, Wtf2, b_ff2, ffout, nullptr, nullptr, nullptr, nullptr, F_, H_, 0, 1, 1);

    // ===== LN2(ln1 + ff) =====
    addln_kernel<<<Rtot, 256, 0, stream>>>(ln1, ffout, g_ln2, b_ln2, out);
}

// Round 8
// 426.225 us; speedup vs baseline: 1.0803x; 1.0803x over previous
//
#include <hip/hip_runtime.h>
#include <math.h>

#define ALPHA 0.2f
#define NEGV  -9e15f
#define EPSV  1e-5f

constexpr int B_ = 2, N_ = 4096, F_ = 256, H_ = 1024;
constexpr int SPLIT_ = 16;   // colstats i-split
constexpr int SPLITJ_ = 4;   // attention j-split

typedef __attribute__((ext_vector_type(4))) float f32x4;
typedef __attribute__((ext_vector_type(8))) short s16x8;

__device__ __forceinline__ unsigned short f2bf(float f) {
    unsigned u = __builtin_bit_cast(unsigned, f);
    u += 0x7fffu + ((u >> 16) & 1u);
    return (unsigned short)(u >> 16);
}
__device__ __forceinline__ float bf2f(unsigned short h) {
    unsigned u = ((unsigned)h) << 16;
    return __builtin_bit_cast(float, u);
}

// ---------------- batched weight transpose + bf16 (+ zero of Wh scratch) -------
__global__ __launch_bounds__(256) void transp_all_kernel(
    const float* __restrict__ W1, const float* __restrict__ W2,
    const float* __restrict__ F1s, const float* __restrict__ F2s,
    unsigned short* __restrict__ D1, unsigned short* __restrict__ D2,
    unsigned short* __restrict__ D3, unsigned short* __restrict__ D4,
    float* __restrict__ zeroDst)
{
    const int mi = blockIdx.z;
    const int t = threadIdx.x;
    if (mi == 4) {
        const int bid = blockIdx.y * 16 + blockIdx.x;
        if (bid < 32) {
            const int i = (bid * 256 + t) * 4;
            *(float4*)&zeroDst[i] = make_float4(0.f, 0.f, 0.f, 0.f);
        }
        return;
    }
    const float* src; unsigned short* dst; int R, Cc;
    if (mi == 0)      { src = W1;  dst = D1; R = 256;  Cc = 256; }
    else if (mi == 1) { src = W2;  dst = D2; R = 256;  Cc = 256; }
    else if (mi == 2) { src = F1s; dst = D3; R = 256;  Cc = 1024; }
    else              { src = F2s; dst = D4; R = 1024; Cc = 256; }
    const int r0 = blockIdx.x * 64, c0 = blockIdx.y * 64;
    if (r0 >= R || c0 >= Cc) return;

    __shared__ float T[64][65];
    #pragma unroll
    for (int s = 0; s < 4; ++s) {
        const int rr = s * 16 + (t >> 4);
        const int cq = t & 15;
        const float4 v = *(const float4*)&src[(size_t)(r0 + rr) * Cc + c0 + cq * 4];
        T[rr][cq * 4 + 0] = v.x; T[rr][cq * 4 + 1] = v.y;
        T[rr][cq * 4 + 2] = v.z; T[rr][cq * 4 + 3] = v.w;
    }
    __syncthreads();
    #pragma unroll
    for (int s = 0; s < 4; ++s) {
        const int cr = s * 16 + (t >> 4);
        const int rq = t & 15;
        ushort4 o;
        o.x = f2bf(T[rq * 4 + 0][cr]);
        o.y = f2bf(T[rq * 4 + 1][cr]);
        o.z = f2bf(T[rq * 4 + 2][cr]);
        o.w = f2bf(T[rq * 4 + 3][cr]);
        *(ushort4*)&dst[(size_t)(c0 + cr) * R + r0 + rq * 4] = o;
    }
}

// ---------------- 128x128 bf16 MFMA GEMM (M fixed 8192) ------------------------
__global__ __launch_bounds__(256) void gemm128_kernel(
    const void* __restrict__ Ap, const unsigned short* __restrict__ Wt,
    const float* __restrict__ bias, void* __restrict__ Cp,
    unsigned short* __restrict__ Tout, const float* __restrict__ wha,
    float* __restrict__ Wh1, float* __restrict__ Wh2,
    int Nc, int K, int relu, int a_bf16, int c_mode)
{
    __shared__ unsigned short As[128 * 72];
    __shared__ unsigned short Bs[128 * 72];
    const int t = threadIdx.x;
    const int w = t >> 6, l = t & 63;
    const int quad = l >> 4, l15 = l & 15;
    const int wr = w & 1, wc = w >> 1;
    const int row0 = blockIdx.y * 128, col0 = blockIdx.x * 128;
    const int sr = t >> 1;
    const int sk = (t & 1) * 32;

    f32x4 acc[4][4];
    #pragma unroll
    for (int it = 0; it < 4; ++it)
        #pragma unroll
        for (int ft = 0; ft < 4; ++ft) acc[it][ft] = (f32x4)(0.f);

    for (int k0 = 0; k0 < K; k0 += 64) {
        if (a_bf16) {
            const unsigned short* ap =
                (const unsigned short*)Ap + (size_t)(row0 + sr) * K + k0 + sk;
            #pragma unroll
            for (int u = 0; u < 4; ++u)
                *(s16x8*)&As[sr * 72 + sk + u * 8] = *(const s16x8*)(ap + u * 8);
        } else {
            const float* ap = (const float*)Ap + (size_t)(row0 + sr) * K + k0 + sk;
            #pragma unroll
            for (int u = 0; u < 8; ++u) {
                const float4 v = *(const float4*)(ap + u * 4);
                ushort4 o;
                o.x = f2bf(v.x); o.y = f2bf(v.y); o.z = f2bf(v.z); o.w = f2bf(v.w);
                *(ushort4*)&As[sr * 72 + sk + u * 4] = o;
            }
        }
        {
            const unsigned short* bp = Wt + (size_t)(col0 + sr) * K + k0 + sk;
            #pragma unroll
            for (int u = 0; u < 4; ++u)
                *(s16x8*)&Bs[sr * 72 + sk + u * 8] = *(const s16x8*)(bp + u * 8);
        }
        __syncthreads();
        #pragma unroll
        for (int ks = 0; ks < 64; ks += 32) {
            s16x8 af[4], bf[4];
            #pragma unroll
            for (int it = 0; it < 4; ++it)
                af[it] = *(const s16x8*)&As[(wr * 64 + it * 16 + l15) * 72 + ks + quad * 8];
            #pragma unroll
            for (int ft = 0; ft < 4; ++ft)
                bf[ft] = *(const s16x8*)&Bs[(wc * 64 + ft * 16 + l15) * 72 + ks + quad * 8];
            #pragma unroll
            for (int ft = 0; ft < 4; ++ft)
                #pragma unroll
                for (int it = 0; it < 4; ++it)
                    acc[it][ft] = __builtin_amdgcn_mfma_f32_16x16x32_bf16(
                        af[it], bf[ft], acc[it][ft], 0, 0, 0);
        }
        __syncthreads();
    }

    if (c_mode) {
        #pragma unroll
        for (int ft = 0; ft < 4; ++ft) {
            const int col = col0 + wc * 64 + ft * 16 + l15;
            const float bv = bias ? bias[col] : 0.f;
            #pragma unroll
            for (int it = 0; it < 4; ++it) {
                const int rbase = row0 + wr * 64 + it * 16 + quad * 4;
                #pragma unroll
                for (int rr = 0; rr < 4; ++rr) {
                    float v = acc[it][ft][rr] + bv;
                    if (relu) v = fmaxf(v, 0.f);
                    if (c_mode == 2)
                        ((unsigned short*)Cp)[(size_t)(rbase + rr) * Nc + col] = f2bf(v);
                    else
                        ((float*)Cp)[(size_t)(rbase + rr) * Nc + col] = v;
                }
            }
        }
    }

    if (Tout) {
        const int bb = row0 >> 12;
        #pragma unroll
        for (int ft = 0; ft < 4; ++ft) {
            const int col = col0 + wc * 64 + ft * 16 + l15;
            #pragma unroll
            for (int it = 0; it < 4; ++it) {
                const int ibase = (row0 & (N_ - 1)) + wr * 64 + it * 16 + quad * 4;
                ushort4 o;
                o.x = f2bf(acc[it][ft][0]); o.y = f2bf(acc[it][ft][1]);
                o.z = f2bf(acc[it][ft][2]); o.w = f2bf(acc[it][ft][3]);
                *(ushort4*)&Tout[((size_t)bb * F_ + col) * N_ + ibase] = o;
            }
        }
    }

    if (wha) {
        float a1v[4], a2v[4];
        #pragma unroll
        for (int ft = 0; ft < 4; ++ft) {
            const int col = col0 + wc * 64 + ft * 16 + l15;
            a1v[ft] = wha[col];
            a2v[ft] = wha[F_ + col];
        }
        #pragma unroll
        for (int it = 0; it < 4; ++it)
            #pragma unroll
            for (int rr = 0; rr < 4; ++rr) {
                float s1 = 0.f, s2 = 0.f;
                #pragma unroll
                for (int ft = 0; ft < 4; ++ft) {
                    s1 += acc[it][ft][rr] * a1v[ft];
                    s2 += acc[it][ft][rr] * a2v[ft];
                }
                #pragma unroll
                for (int mkk = 1; mkk < 16; mkk <<= 1) {
                    s1 += __shfl_xor(s1, mkk);
                    s2 += __shfl_xor(s2, mkk);
                }
                if (l15 == 0) {
                    const int row = row0 + wr * 64 + it * 16 + quad * 4 + rr;
                    atomicAdd(&Wh1[row], s1);
                    atomicAdd(&Wh2[row], s2);
                }
            }
    }
}

// ---------------- layer-1: adj -> stats + bitmask (fused, 8-wide ILP) ----------
__global__ __launch_bounds__(256) void colstats_adj_kernel(
    const int* __restrict__ adj, unsigned long long* __restrict__ maskOut,
    const float* __restrict__ Wh1, const float* __restrict__ Wh2,
    float* __restrict__ pM, float* __restrict__ pS)
{
    const int t = threadIdx.x;
    const int j = blockIdx.x * 256 + t;
    const int sp = blockIdx.y;
    const int b = blockIdx.z;
    const int i0 = sp * (N_ / SPLIT_);
    const int w = t >> 6, l = t & 63;
    const float w2 = Wh2[b * N_ + j];
    const float* __restrict__ w1p = Wh1 + b * N_ + i0;
    const int* __restrict__ ap = adj + ((size_t)b * N_ + i0) * N_ + j;

    float m = -3.4e38f, s = 0.f;
    for (int c = 0; c < N_ / SPLIT_; c += 8) {
        int v[8];
        #pragma unroll
        for (int u = 0; u < 8; ++u) v[u] = ap[(size_t)(c + u) * N_];
        float x[8];
        #pragma unroll
        for (int u = 0; u < 8; ++u) {
            const bool act = v[u] > 0;
            const unsigned long long bm = __ballot(act);
            if (l == 0)
                maskOut[((size_t)b * N_ + i0 + c + u) * (N_ / 64) + blockIdx.x * 4 + w] = bm;
            const float e0 = w1p[c + u] + w2;
            const float e = fmaxf(e0, ALPHA * e0);
            x[u] = act ? e : NEGV;
        }
        const float cm = fmaxf(fmaxf(fmaxf(x[0], x[1]), fmaxf(x[2], x[3])),
                               fmaxf(fmaxf(x[4], x[5]), fmaxf(x[6], x[7])));
        const float nm = fmaxf(m, cm);
        float cs = 0.f;
        #pragma unroll
        for (int u = 0; u < 8; ++u) cs += __expf(x[u] - nm);
        s = s * __expf(m - nm) + cs;
        m = nm;
    }
    pM[((size_t)b * SPLIT_ + sp) * N_ + j] = m;
    pS[((size_t)b * SPLIT_ + sp) * N_ + j] = s;
}

// ---------------- layer-2: stats from bitmask ----------------------------------
__global__ __launch_bounds__(256) void colstats3_kernel(
    const unsigned long long* __restrict__ mask,
    const float* __restrict__ Wh1, const float* __restrict__ Wh2,
    float* __restrict__ pM, float* __restrict__ pS)
{
    const int t = threadIdx.x;
    const int j = blockIdx.x * 256 + t;
    const int sp = blockIdx.y;
    const int b = blockIdx.z;
    const int i0 = sp * (N_ / SPLIT_);
    const int w = t >> 6;
    const int jbit = t & 63;
    const float w2 = Wh2[b * N_ + j];
    const unsigned long long* __restrict__ mbase =
        mask + ((size_t)b * N_ + i0) * (N_ / 64) + blockIdx.x * 4 + w;
    const float* __restrict__ w1p = Wh1 + b * N_ + i0;

    float m = -3.4e38f, s = 0.f;
    for (int c = 0; c < N_ / SPLIT_; c += 8) {
        float x[8];
        #pragma unroll
        for (int u = 0; u < 8; ++u) {
            const unsigned long long mw = mbase[(size_t)(c + u) * (N_ / 64)];
            const float e0 = w1p[c + u] + w2;
            const float e = fmaxf(e0, ALPHA * e0);
            x[u] = ((mw >> jbit) & 1ull) ? e : NEGV;
        }
        const float cm = fmaxf(fmaxf(fmaxf(x[0], x[1]), fmaxf(x[2], x[3])),
                               fmaxf(fmaxf(x[4], x[5]), fmaxf(x[6], x[7])));
        const float nm = fmaxf(m, cm);
        float cs = 0.f;
        #pragma unroll
        for (int u = 0; u < 8; ++u) cs += __expf(x[u] - nm);
        s = s * __expf(m - nm) + cs;
        m = nm;
    }
    pM[((size_t)b * SPLIT_ + sp) * N_ + j] = m;
    pS[((size_t)b * SPLIT_ + sp) * N_ + j] = s;
}

// ---------------- attention matmul: LDS-B pipelined + fused colfin + bf16 out --
// grid (N/64, SPLITJ, B), block 256 (4 waves).
__global__ __launch_bounds__(256) void att_mfma4_kernel(
    const unsigned short* __restrict__ mask16, const unsigned short* __restrict__ Wht,
    const float* __restrict__ Wh1, const float* __restrict__ Wh2,
    const float* __restrict__ pM, const float* __restrict__ pS,
    unsigned short* __restrict__ partb)
{
    __shared__ unsigned short Bs[256 * 72];
    __shared__ unsigned short Ps[64 * 72];
    __shared__ float w2s[1024];
    __shared__ float mos[1024];

    const int t = threadIdx.x;
    const int w = t >> 6, l = t & 63;
    const int quad = l >> 4, l15 = l & 15;
    const int b = blockIdx.z;
    const int i0 = blockIdx.x * 64;
    const int sp = blockIdx.y;
    const int jbase = sp * (N_ / SPLITJ_);

    const int pi = t >> 2;
    const int pj4 = t & 3;
    const float w1i = Wh1[b * N_ + i0 + pi];
    const unsigned short* __restrict__ mrow =
        mask16 + ((size_t)b * N_ + i0 + pi) * (N_ / 16);
    const unsigned short* __restrict__ WhtB = Wht + (size_t)b * F_ * N_;

    // ---- fused colfin: mo = m + ln(sum) for this block's 1024-j range ----
    {
        const int jg = jbase + t * 4;
        float4 m4 = make_float4(-3.4e38f, -3.4e38f, -3.4e38f, -3.4e38f);
        #pragma unroll
        for (int s = 0; s < SPLIT_; ++s) {
            const float4 v = *(const float4*)&pM[((size_t)b * SPLIT_ + s) * N_ + jg];
            m4.x = fmaxf(m4.x, v.x); m4.y = fmaxf(m4.y, v.y);
            m4.z = fmaxf(m4.z, v.z); m4.w = fmaxf(m4.w, v.w);
        }
        float4 s4 = make_float4(0.f, 0.f, 0.f, 0.f);
        #pragma unroll
        for (int s = 0; s < SPLIT_; ++s) {
            const float4 vm = *(const float4*)&pM[((size_t)b * SPLIT_ + s) * N_ + jg];
            const float4 vs = *(const float4*)&pS[((size_t)b * SPLIT_ + s) * N_ + jg];
            s4.x += vs.x * __expf(vm.x - m4.x);
            s4.y += vs.y * __expf(vm.y - m4.y);
            s4.z += vs.z * __expf(vm.z - m4.z);
            s4.w += vs.w * __expf(vm.w - m4.w);
        }
        float4 mo4;
        mo4.x = m4.x + __logf(s4.x);
        mo4.y = m4.y + __logf(s4.y);
        mo4.z = m4.z + __logf(s4.z);
        mo4.w = m4.w + __logf(s4.w);
        *(float4*)&mos[t * 4] = mo4;
        *(float4*)&w2s[t * 4] = *(const float4*)&Wh2[b * N_ + jg];
    }

    f32x4 acc[4][4];
    #pragma unroll
    for (int it = 0; it < 4; ++it)
        #pragma unroll
        for (int ft = 0; ft < 4; ++ft) acc[it][ft] = (f32x4)(0.f);

    const int f0s = t >> 3;
    const int prt = (t & 7) * 8;
    s16x8 breg[8];
    // prefetch iter-0 B tile + mask
    #pragma unroll
    for (int s = 0; s < 8; ++s)
        breg[s] = *(const s16x8*)&WhtB[(size_t)(f0s + s * 32) * N_ + jbase + prt];
    unsigned short mb_cur = mrow[jbase / 16 + pj4];
    __syncthreads();   // stats LDS ready

    constexpr int NITER = (N_ / SPLITJ_) / 64;
    for (int itr = 0; itr < NITER; ++itr) {
        const int jb = jbase + itr * 64;
        // ---- write B tile from prefetched regs ----
        #pragma unroll
        for (int s = 0; s < 8; ++s)
            *(s16x8*)&Bs[(f0s + s * 32) * 72 + prt] = breg[s];
        // ---- P gen (stats from LDS) ----
        {
            const unsigned mb = mb_cur;
            const int jl = itr * 64 + pj4 * 16;
            #pragma unroll
            for (int u4 = 0; u4 < 4; ++u4) {
                const float4 w2v = *(const float4*)&w2s[jl + u4 * 4];
                const float4 mov = *(const float4*)&mos[jl + u4 * 4];
                ushort4 o;
                unsigned short* op = &o.x;
                #pragma unroll
                for (int u = 0; u < 4; ++u) {
                    const float xw = w1i + (&w2v.x)[u];
                    const float e = fmaxf(xw, ALPHA * xw);
                    const float x2 = ((mb >> (u4 * 4 + u)) & 1u) ? e : NEGV;
                    op[u] = f2bf(__expf(x2 - (&mov.x)[u]));
                }
                *(ushort4*)&Ps[pi * 72 + pj4 * 16 + u4 * 4] = o;
            }
        }
        __syncthreads();
        // ---- prefetch next iter (overlaps MFMA phase) ----
        if (itr + 1 < NITER) {
            const int jn = jb + 64;
            #pragma unroll
            for (int s = 0; s < 8; ++s)
                breg[s] = *(const s16x8*)&WhtB[(size_t)(f0s + s * 32) * N_ + jn + prt];
            mb_cur = mrow[jn / 16 + pj4];
        }
        // ---- MFMA ----
        #pragma unroll
        for (int ks = 0; ks < 64; ks += 32) {
            s16x8 af[4];
            #pragma unroll
            for (int it = 0; it < 4; ++it)
                af[it] = *(const s16x8*)&Ps[(it * 16 + l15) * 72 + ks + quad * 8];
            #pragma unroll
            for (int ft = 0; ft < 4; ++ft) {
                const s16x8 bf =
                    *(const s16x8*)&Bs[(w * 64 + ft * 16 + l15) * 72 + ks + quad * 8];
                #pragma unroll
                for (int it = 0; it < 4; ++it)
                    acc[it][ft] = __builtin_amdgcn_mfma_f32_16x16x32_bf16(
                        af[it], bf, acc[it][ft], 0, 0, 0);
            }
        }
        __syncthreads();
    }

    // ---- epilogue: bf16 partials [sp][b][i][f] ----
    unsigned short* __restrict__ pout = partb + ((size_t)sp * B_ + b) * N_ * F_;
    #pragma unroll
    for (int it = 0; it < 4; ++it)
        #pragma unroll
        for (int ft = 0; ft < 4; ++ft) {
            const int col = w * 64 + ft * 16 + l15;
            #pragma unroll
            for (int rr = 0; rr < 4; ++rr) {
                const int row = i0 + it * 16 + quad * 4 + rr;
                pout[(size_t)row * F_ + col] = f2bf(acc[it][ft][rr]);
            }
        }
}

// ---------------- bf16 partial reduction (4 splits) -> bf16 --------------------
__global__ __launch_bounds__(256) void reduceb_kernel(
    const unsigned short* __restrict__ p, unsigned short* __restrict__ outb)
{
    const size_t i = ((size_t)blockIdx.x * 256 + threadIdx.x) * 8;
    const size_t S = (size_t)B_ * N_ * F_;
    float acc[8] = {};
    #pragma unroll
    for (int u = 0; u < 4; ++u) {
        const ushort4 a = *(const ushort4*)&p[i + u * S];
        const ushort4 c = *(const ushort4*)&p[i + u * S + 4];
        acc[0] += bf2f(a.x); acc[1] += bf2f(a.y);
        acc[2] += bf2f(a.z); acc[3] += bf2f(a.w);
        acc[4] += bf2f(c.x); acc[5] += bf2f(c.y);
        acc[6] += bf2f(c.z); acc[7] += bf2f(c.w);
    }
    ushort4 o0, o1;
    o0.x = f2bf(acc[0]); o0.y = f2bf(acc[1]); o0.z = f2bf(acc[2]); o0.w = f2bf(acc[3]);
    o1.x = f2bf(acc[4]); o1.y = f2bf(acc[5]); o1.z = f2bf(acc[6]); o1.w = f2bf(acc[7]);
    *(ushort4*)&outb[i] = o0;
    *(ushort4*)&outb[i + 4] = o1;
}

// ---------------- x + 4-way bf16 partial sum + LayerNorm -> fp32 + bf16 --------
__global__ __launch_bounds__(256) void addln4_kernel(
    const float* __restrict__ X, const unsigned short* __restrict__ pb,
    const float* __restrict__ g, const float* __restrict__ bta,
    float* __restrict__ outf, unsigned short* __restrict__ outb)
{
    const int row = blockIdx.x;
    const int t = threadIdx.x;
    const size_t idx = (size_t)row * F_ + t;
    const size_t S = (size_t)B_ * N_ * F_;
    const float v = X[idx] + bf2f(pb[idx]) + bf2f(pb[idx + S])
                  + bf2f(pb[idx + 2 * S]) + bf2f(pb[idx + 3 * S]);
    float s1 = v, s2 = v * v;
    #pragma unroll
    for (int off = 32; off > 0; off >>= 1) {
        s1 += __shfl_down(s1, off);
        s2 += __shfl_down(s2, off);
    }
    __shared__ float r1[4], r2[4];
    __shared__ float mu_s, rs_s;
    const int wid = t >> 6, lane = t & 63;
    if (lane == 0) { r1[wid] = s1; r2[wid] = s2; }
    __syncthreads();
    if (t == 0) {
        const float a = r1[0] + r1[1] + r1[2] + r1[3];
        const float q = r2[0] + r2[1] + r2[2] + r2[3];
        const float mu = a * (1.f / F_);
        const float var = q * (1.f / F_) - mu * mu;
        mu_s = mu;
        rs_s = rsqrtf(var + EPSV);
    }
    __syncthreads();
    const float r = (v - mu_s) * rs_s * g[t] + bta[t];
    outf[idx] = r;
    outb[idx] = f2bf(r);
}

// ---------------- residual add + LayerNorm (final) -----------------------------
__global__ __launch_bounds__(256) void addln_kernel(
    const float* __restrict__ X, const float* __restrict__ Y,
    const float* __restrict__ g, const float* __restrict__ bta,
    float* __restrict__ out)
{
    const int row = blockIdx.x;
    const int t = threadIdx.x;
    const size_t idx = (size_t)row * F_ + t;
    const float v = X[idx] + Y[idx];
    float s1 = v, s2 = v * v;
    #pragma unroll
    for (int off = 32; off > 0; off >>= 1) {
        s1 += __shfl_down(s1, off);
        s2 += __shfl_down(s2, off);
    }
    __shared__ float r1[4], r2[4];
    __shared__ float mu_s, rs_s;
    const int wid = t >> 6, lane = t & 63;
    if (lane == 0) { r1[wid] = s1; r2[wid] = s2; }
    __syncthreads();
    if (t == 0) {
        const float a = r1[0] + r1[1] + r1[2] + r1[3];
        const float q = r2[0] + r2[1] + r2[2] + r2[3];
        const float mu = a * (1.f / F_);
        const float var = q * (1.f / F_) - mu * mu;
        mu_s = mu;
        rs_s = rsqrtf(var + EPSV);
    }
    __syncthreads();
    out[idx] = (v - mu_s) * rs_s * g[t] + bta[t];
}

// -------------------------------------------------------------------------------
extern "C" void kernel_launch(void* const* d_in, const int* in_sizes, int n_in,
                              void* d_out, int out_size, void* d_ws, size_t ws_size,
                              hipStream_t stream)
{
    const float* x     = (const float*)d_in[0];
    const int*   adj   = (const int*)d_in[1];
    const float* W1    = (const float*)d_in[2];
    const float* a1    = (const float*)d_in[3];
    const float* W2    = (const float*)d_in[4];
    const float* a2    = (const float*)d_in[5];
    const float* w_ff1 = (const float*)d_in[6];
    const float* b_ff1 = (const float*)d_in[7];
    const float* w_ff2 = (const float*)d_in[8];
    const float* b_ff2 = (const float*)d_in[9];
    const float* g_ln1 = (const float*)d_in[10];
    const float* b_ln1 = (const float*)d_in[11];
    const float* g_ln2 = (const float*)d_in[12];
    const float* b_ln2 = (const float*)d_in[13];
    float* out = (float*)d_out;

    const int Rtot = B_ * N_;             // 8192
    char* wsb = (char*)d_ws;
    unsigned short* partb = (unsigned short*)wsb;                // 16 MB
    float* ln1   = (float*)(wsb + 16777216);                     // 8 MB
    float* ffout = (float*)(wsb + 25165824);                     // 8 MB
    unsigned short* mid  = (unsigned short*)(wsb + 33554432);    // 16 MB
    unsigned short* ln1b = (unsigned short*)(wsb + 50331648);    // 4 MB
    unsigned short* g1b  = (unsigned short*)(wsb + 54525952);    // 4 MB
    unsigned short* Wht  = (unsigned short*)(wsb + 58720256);    // 4 MB
    unsigned long long* mask = (unsigned long long*)(wsb + 62914560); // 4 MB
    unsigned short* mask16 = (unsigned short*)mask;
    unsigned short* Wt1  = (unsigned short*)(wsb + 67108864);    // 128 KB
    unsigned short* Wt2  = Wt1 + 65536;                          // 128 KB
    unsigned short* Wtf1 = Wt2 + 65536;                          // 512 KB
    unsigned short* Wtf2 = Wtf1 + 262144;                        // 512 KB
    float* WhA1 = (float*)(wsb + 69206016);                      // 32 KB zeroed
    float* WhA2 = WhA1 + 8192;
    float* WhB1 = WhA2 + 8192;
    float* WhB2 = WhB1 + 8192;
    float* pM   = (float*)(wsb + 69337088);                      // 512 KB
    float* pS   = (float*)(wsb + 69861376);                      // 512 KB

    const dim3 statsG(N_ / 256, SPLIT_, B_);
    const dim3 attG(N_ / 64, SPLITJ_, B_);

    // ===== prologue: weight transposes + zero atomic targets (one kernel) =====
    transp_all_kernel<<<dim3(16, 16, 5), 256, 0, stream>>>(
        W1, W2, w_ff1, w_ff2, Wt1, Wt2, Wtf1, Wtf2, WhA1);

    // ===== GAT layer 1 =====
    gemm128_kernel<<<dim3(2, 64), 256, 0, stream>>>(
        x, Wt1, nullptr, nullptr, Wht, a1, WhA1, WhA2, F_, F_, 0, 0, 0);
    colstats_adj_kernel<<<statsG, 256, 0, stream>>>(adj, mask, WhA1, WhA2, pM, pS);
    att_mfma4_kernel<<<attG, 256, 0, stream>>>(mask16, Wht, WhA1, WhA2, pM, pS, partb);
    reduceb_kernel<<<1024, 256, 0, stream>>>(partb, g1b);

    // ===== GAT layer 2 (mask reused) =====
    gemm128_kernel<<<dim3(2, 64), 256, 0, stream>>>(
        g1b, Wt2, nullptr, nullptr, Wht, a2, WhB1, WhB2, F_, F_, 0, 1, 0);
    colstats3_kernel<<<statsG, 256, 0, stream>>>(mask, WhB1, WhB2, pM, pS);
    att_mfma4_kernel<<<attG, 256, 0, stream>>>(mask16, Wht, WhB1, WhB2, pM, pS, partb);

    // ===== LN1(x + sum of 4 bf16 partials) -> ln1 fp32 + ln1b bf16 =====
    addln4_kernel<<<Rtot, 256, 0, stream>>>(x, partb, g_ln1, b_ln1, ln1, ln1b);

    // ===== FFN =====
    gemm128_kernel<<<dim3(8, 64), 256, 0, stream>>>(
        ln1b, Wtf1, b_ff1, mid, nullptr, nullptr, nullptr, nullptr, H_, F_, 1, 1, 2);
    gemm128_kernel<<<dim3(2, 64), 256, 0, stream>>>(
        mid, Wtf2, b_ff2, ffout, nullptr, nullptr, nullptr, nullptr, F_, H_, 0, 1, 1);

    // ===== LN2(ln1 + ff) =====
    addln_kernel<<<Rtot, 256, 0, stream>>>(ln1, ffout, g_ln2, b_ln2, out);
}